// Round 1
// baseline (602.831 us; speedup 1.0000x reference)
//
#include <hip/hip_runtime.h>
#include <stdint.h>

typedef __bf16 bf8 __attribute__((ext_vector_type(8)));
typedef float f32x4 __attribute__((ext_vector_type(4)));

#define T_TOK 2048
#define HDIM 1024
#define IDIM 4096
#define NE 8
#define TM 128
#define TN 64
#define BK 64
#define CAP 5120   // 4096 + 8*128 pad
#define MT_MAX 40

__device__ __forceinline__ float gelu_tanh(float x) {
  float u = 0.7978845608028654f * (x + 0.044715f * x * x * x);
  float t = 1.0f - 2.0f / (1.0f + __expf(2.0f * u));  // tanh(u)
  return 0.5f * x * (1.0f + t);
}

__device__ __forceinline__ uint32_t pk(float a, float b) {
  __bf16 x = (__bf16)a, y = (__bf16)b;
  unsigned short ux = __builtin_bit_cast(unsigned short, x);
  unsigned short uy = __builtin_bit_cast(unsigned short, y);
  return (uint32_t)ux | ((uint32_t)uy << 16);
}

// async global->LDS DMA, 16B per lane. LDS dest must be wave-uniform base +
// lane*16 (m104/m108).
__device__ __forceinline__ void gl2lds16(const void* g, void* l) {
  __builtin_amdgcn_global_load_lds((const __attribute__((address_space(1))) uint32_t*)g,
                                   (__attribute__((address_space(3))) uint32_t*)l, 16, 0, 0);
}

// ---------------- router: one wave per token; also converts x -> bf16 ----------------
__global__ __launch_bounds__(64) void router_kernel(
    const float* __restrict__ x, const float* __restrict__ Wg,
    float* __restrict__ logits_out, int* __restrict__ sel, float* __restrict__ wts,
    __bf16* __restrict__ xbf)
{
  const int t = blockIdx.x;
  const int lane = threadIdx.x;
  float acc[NE];
#pragma unroll
  for (int e = 0; e < NE; ++e) acc[e] = 0.f;
  const float* xr = x + (size_t)t * HDIM;
  __bf16* xbr = xbf + (size_t)t * HDIM;
#pragma unroll
  for (int rep = 0; rep < 4; ++rep) {
    int hb = rep * 256 + lane * 4;
    float4 f = *(const float4*)(xr + hb);
    uint2 w; w.x = pk(f.x, f.y); w.y = pk(f.z, f.w);
    *(uint2*)(xbr + hb) = w;
    float fv[4] = {f.x, f.y, f.z, f.w};
#pragma unroll
    for (int i = 0; i < 4; ++i) {
      const float* wg = Wg + (size_t)(hb + i) * NE;
      float4 w0 = *(const float4*)wg;
      float4 w1 = *(const float4*)(wg + 4);
      acc[0] += fv[i] * w0.x; acc[1] += fv[i] * w0.y;
      acc[2] += fv[i] * w0.z; acc[3] += fv[i] * w0.w;
      acc[4] += fv[i] * w1.x; acc[5] += fv[i] * w1.y;
      acc[6] += fv[i] * w1.z; acc[7] += fv[i] * w1.w;
    }
  }
#pragma unroll
  for (int off = 32; off > 0; off >>= 1) {
#pragma unroll
    for (int e = 0; e < NE; ++e) acc[e] += __shfl_down(acc[e], off);
  }
  if (lane == 0) {
    float* lo = logits_out + (size_t)t * NE;
#pragma unroll
    for (int e = 0; e < NE; ++e) lo[e] = acc[e];
    int i0 = 0; float v0 = acc[0];
#pragma unroll
    for (int e = 1; e < NE; ++e) if (acc[e] > v0) { v0 = acc[e]; i0 = e; }
    int i1 = -1; float v1 = -3.4e38f;
#pragma unroll
    for (int e = 0; e < NE; ++e) {
      if (e != i0 && acc[e] > v1) { v1 = acc[e]; i1 = e; }
    }
    float ex = __expf(v1 - v0);
    float w0 = 1.0f / (1.0f + ex);
    sel[2 * t] = i0; sel[2 * t + 1] = i1;
    wts[2 * t] = w0; wts[2 * t + 1] = 1.0f - w0;
  }
}

// ---------------- build per-expert slot groups (1 block) ----------------
// pad slots get slot_map = -1 (clamped for staging; slot_w=0 kills them).
// inv_map[2t+k] = slot position of token t's k-th expert (for combine).
__global__ __launch_bounds__(256) void build_groups(
    const int* __restrict__ sel, const float* __restrict__ wts,
    int* __restrict__ slot_map, float* __restrict__ slot_w, int* __restrict__ meta,
    int* __restrict__ inv_map)
{
  __shared__ int cnt[NE], cur[NE], offp[NE + 1];
  const int tid = threadIdx.x;
  if (tid < NE) { cnt[tid] = 0; cur[tid] = 0; }
  __syncthreads();
  for (int t = tid; t < T_TOK; t += 256) {
    atomicAdd(&cnt[sel[2 * t]], 1);
    atomicAdd(&cnt[sel[2 * t + 1]], 1);
  }
  __syncthreads();
  if (tid == 0) {
    int o = 0;
    for (int e = 0; e < NE; ++e) { offp[e] = o; o += ((cnt[e] + TM - 1) / TM) * TM; }
    offp[NE] = o;
    for (int e = 0; e <= NE; ++e) meta[e] = offp[e];
    meta[NE + 1] = o;
  }
  __syncthreads();
  for (int p = tid; p < CAP; p += 256) { slot_map[p] = -1; slot_w[p] = 0.f; }
  __syncthreads();
  for (int t = tid; t < T_TOK; t += 256) {
#pragma unroll
    for (int k = 0; k < 2; ++k) {
      int e = sel[2 * t + k];
      int pos = offp[e] + atomicAdd(&cur[e], 1);
      slot_map[pos] = t;
      slot_w[pos] = wts[2 * t + k];
      inv_map[2 * t + k] = pos;
    }
  }
}

// ---------------- prep v2: fp32 [K][N] -> bf16 [N][K], 64k x 128n tiles ----------------
// LDS row = 40 dwords (32 k-pair dwords + 8 pad). k-quad b64 stores at
// XOR-swizzled 16B chunk (c ^ (n&7)) -> <=2-way conflicts; b128 reads conflict-free.
template <int K, int N>
__device__ __forceinline__ void transpose_tile64x128(const float* __restrict__ src,
                                                     __bf16* __restrict__ dst,
                                                     int kt, int nt, uint32_t* lds)
{
  const int tid = threadIdx.x;
  const int k0 = kt * 64, n0 = nt * 128;
#pragma unroll
  for (int rep = 0; rep < 2; ++rep) {
    int k4 = (tid >> 5) + rep * 8;        // k-quad index 0..15
    int nc = tid & 31;                    // float4 chunk along n
    const float* p = src + (size_t)(k0 + k4 * 4) * N + n0 + nc * 4;
    float4 f0 = *(const float4*)p;
    float4 f1 = *(const float4*)(p + N);
    float4 f2 = *(const float4*)(p + 2 * N);
    float4 f3 = *(const float4*)(p + 3 * N);
    float a0[4] = {f0.x, f0.y, f0.z, f0.w};
    float a1[4] = {f1.x, f1.y, f1.z, f1.w};
    float a2[4] = {f2.x, f2.y, f2.z, f2.w};
    float a3[4] = {f3.x, f3.y, f3.z, f3.w};
    const int c = k4 >> 1, h = k4 & 1;
#pragma unroll
    for (int i = 0; i < 4; ++i) {
      int n = nc * 4 + i;
      uint32_t* q = &lds[n * 40 + ((c ^ (n & 7)) << 2) + (h << 1)];
      q[0] = pk(a0[i], a1[i]);
      q[1] = pk(a2[i], a3[i]);
    }
  }
  __syncthreads();
#pragma unroll
  for (int rep = 0; rep < 4; ++rep) {
    int n = (tid >> 3) + rep * 32;
    int c = tid & 7;                      // 16B chunk along k (8 bf16)
    uint4 v = *(const uint4*)&lds[n * 40 + ((c ^ (n & 7)) << 2)];
    *(uint4*)(dst + (size_t)(n0 + n) * K + k0 + c * 8) = v;
  }
}

__global__ __launch_bounds__(256) void prep_kernel(
    const float* __restrict__ Win, const float* __restrict__ Wv,
    const float* __restrict__ Wout, __bf16* __restrict__ WinT,
    __bf16* __restrict__ WvT, __bf16* __restrict__ WoutT)
{
  __shared__ uint32_t lds[128 * 40];
  const int b = blockIdx.x;
  if (b < 4096) {
    const int e = b >> 9, t = b & 511;    // 16 kt x 32 nt
    transpose_tile64x128<HDIM, IDIM>(Win + (size_t)e * HDIM * IDIM,
                                     WinT + (size_t)e * IDIM * HDIM, t & 15, t >> 4, lds);
  } else if (b < 8192) {
    const int e = (b - 4096) >> 9, t = b & 511;
    transpose_tile64x128<HDIM, IDIM>(Wv + (size_t)e * HDIM * IDIM,
                                     WvT + (size_t)e * IDIM * HDIM, t & 15, t >> 4, lds);
  } else {
    const int e = (b - 8192) >> 9, t = b & 511;  // 64 kt x 8 nt
    transpose_tile64x128<IDIM, HDIM>(Wout + (size_t)e * IDIM * HDIM,
                                     WoutT + (size_t)e * HDIM * IDIM, t & 63, t >> 6, lds);
  }
}

// ---------------- grouped GEMM1 + GLU (m97-style DMA staging) ----------------
__global__ __launch_bounds__(256) void moe_mlp1(
    const __bf16* __restrict__ xbf, const __bf16* __restrict__ WinT,
    const __bf16* __restrict__ WvT, const int* __restrict__ slot_map,
    const float* __restrict__ slot_w, const int* __restrict__ meta,
    __bf16* __restrict__ act)
{
  const int total = meta[NE + 1];
  // T1: XCD-aware bijective swizzle (grid = 2560, %8==0). Concurrent blocks on
  // one XCD then share tn weight panels -> L2 working set fits 4 MB.
  const int nwg = MT_MAX * (IDIM / TN);
  int bid = blockIdx.x;
  bid = (bid & 7) * (nwg >> 3) + (bid >> 3);
  const int tm = bid % MT_MAX, tn = bid / MT_MAX;
  const int base = tm * TM;
  if (base >= total) return;

  int e = 0;
#pragma unroll
  for (int j = 1; j < NE; ++j) if (base >= meta[j]) e = j;

  __shared__ __align__(16) __bf16 As[TM * BK];   // 16 KB
  __shared__ __align__(16) __bf16 Bg[TN * BK];   // 8 KB
  __shared__ __align__(16) __bf16 Bv[TN * BK];   // 8 KB

  const int tid = threadIdx.x;
  const int lane = tid & 63, wave = tid >> 6;
  const int m16 = lane & 15, q = lane >> 4;
  const int lrow = lane >> 3, lchunk = lane & 7;
  const int bn = tn * TN;

  const char* pA[4]; char* lA[4];
#pragma unroll
  for (int i = 0; i < 4; ++i) {
    int r = wave * 32 + i * 8 + lrow;
    int tok = slot_map[base + r];
    if (tok < 0) tok = 0;                 // pad: load any valid row (w=0 kills it)
    int c = lchunk ^ (r & 7);
    pA[i] = (const char*)(xbf + (size_t)tok * HDIM) + c * 16;
    lA[i] = (char*)As + (wave * 32 + i * 8) * 128 + lane * 16;
  }
  const char* pG[2]; const char* pV[2]; char* lG[2]; char* lV[2];
  const size_t wbase = (size_t)e * IDIM * HDIM;
#pragma unroll
  for (int i = 0; i < 2; ++i) {
    int r = wave * 16 + i * 8 + lrow;
    int c = lchunk ^ (r & 7);
    size_t off = (wbase + (size_t)(bn + r) * HDIM) * 2 + c * 16;
    pG[i] = (const char*)WinT + off;
    pV[i] = (const char*)WvT + off;
    lG[i] = (char*)Bg + (wave * 16 + i * 8) * 128 + lane * 16;
    lV[i] = (char*)Bv + (wave * 16 + i * 8) * 128 + lane * 16;
  }

  const int mh = (wave & 1) * 64, nh = (wave >> 1) * 32;
  int aoff[2][4], boff[2][2];
#pragma unroll
  for (int s = 0; s < 2; ++s) {
    int qc = s * 4 + q;
#pragma unroll
    for (int f = 0; f < 4; ++f) {
      int r = mh + f * 16 + m16;
      aoff[s][f] = r * 128 + ((qc ^ (r & 7)) * 16);
    }
#pragma unroll
    for (int j = 0; j < 2; ++j) {
      int r = nh + j * 16 + m16;
      boff[s][j] = r * 128 + ((qc ^ (r & 7)) * 16);
    }
  }

  f32x4 acc[2][2][4];
#pragma unroll
  for (int mt = 0; mt < 2; ++mt)
#pragma unroll
    for (int j = 0; j < 2; ++j)
#pragma unroll
      for (int f = 0; f < 4; ++f)
#pragma unroll
        for (int r = 0; r < 4; ++r) acc[mt][j][f][r] = 0.f;

  for (int it = 0; it < HDIM / BK; ++it) {
    __syncthreads();
#pragma unroll
    for (int i = 0; i < 4; ++i) { gl2lds16(pA[i], lA[i]); pA[i] += BK * 2; }
#pragma unroll
    for (int i = 0; i < 2; ++i) { gl2lds16(pG[i], lG[i]); pG[i] += BK * 2; }
#pragma unroll
    for (int i = 0; i < 2; ++i) { gl2lds16(pV[i], lV[i]); pV[i] += BK * 2; }
    __syncthreads();
#pragma unroll
    for (int s = 0; s < 2; ++s) {
      bf8 a[4], g2[2], v2[2];
#pragma unroll
      for (int f = 0; f < 4; ++f)
        a[f] = *(const bf8*)((const char*)As + aoff[s][f]);
#pragma unroll
      for (int j = 0; j < 2; ++j) {
        g2[j] = *(const bf8*)((const char*)Bg + boff[s][j]);
        v2[j] = *(const bf8*)((const char*)Bv + boff[s][j]);
      }
#pragma unroll
      for (int j = 0; j < 2; ++j)
#pragma unroll
        for (int f = 0; f < 4; ++f) {
          acc[0][j][f] = __builtin_amdgcn_mfma_f32_16x16x32_bf16(a[f], g2[j], acc[0][j][f], 0, 0, 0);
          acc[1][j][f] = __builtin_amdgcn_mfma_f32_16x16x32_bf16(a[f], v2[j], acc[1][j][f], 0, 0, 0);
        }
    }
  }

  const int col0 = bn + nh + m16;
#pragma unroll
  for (int f = 0; f < 4; ++f)
#pragma unroll
    for (int r = 0; r < 4; ++r) {
      int row = mh + f * 16 + q * 4 + r;
      int slot = base + row;
      float w = slot_w[slot];
      __bf16* arow = act + (size_t)slot * IDIM + col0;
#pragma unroll
      for (int j = 0; j < 2; ++j)
        arow[j * 16] = (__bf16)(gelu_tanh(acc[0][j][f][r]) * acc[1][j][f][r] * w);
    }
}

// ---------------- grouped GEMM2: plain stores to slot-major y ----------------
__global__ __launch_bounds__(256) void moe_mlp2(
    const __bf16* __restrict__ act, const __bf16* __restrict__ WoutT,
    const int* __restrict__ meta, float* __restrict__ y)
{
  const int total = meta[NE + 1];
  // T1: XCD-aware bijective swizzle (grid = 640, %8==0)
  const int nwg = MT_MAX * (HDIM / TN);
  int bid = blockIdx.x;
  bid = (bid & 7) * (nwg >> 3) + (bid >> 3);
  const int tm = bid % MT_MAX, tn = bid / MT_MAX;
  const int base = tm * TM;
  if (base >= total) return;

  int e = 0;
#pragma unroll
  for (int j = 1; j < NE; ++j) if (base >= meta[j]) e = j;

  __shared__ __align__(16) __bf16 As[TM * BK];   // 16 KB
  __shared__ __align__(16) __bf16 Bs[TN * BK];   // 8 KB

  const int tid = threadIdx.x;
  const int lane = tid & 63, wave = tid >> 6;
  const int m16 = lane & 15, q = lane >> 4;
  const int lrow = lane >> 3, lchunk = lane & 7;
  const int bn = tn * TN;

  const char* pA[4]; char* lA[4];
#pragma unroll
  for (int i = 0; i < 4; ++i) {
    int r = wave * 32 + i * 8 + lrow;
    int c = lchunk ^ (r & 7);
    pA[i] = (const char*)(act + (size_t)(base + r) * IDIM) + c * 16;
    lA[i] = (char*)As + (wave * 32 + i * 8) * 128 + lane * 16;
  }
  const char* pB[2]; char* lB[2];
  const size_t wbase = (size_t)e * HDIM * IDIM;
#pragma unroll
  for (int i = 0; i < 2; ++i) {
    int r = wave * 16 + i * 8 + lrow;
    int c = lchunk ^ (r & 7);
    pB[i] = (const char*)WoutT + (wbase + (size_t)(bn + r) * IDIM) * 2 + c * 16;
    lB[i] = (char*)Bs + (wave * 16 + i * 8) * 128 + lane * 16;
  }

  const int mh = (wave & 1) * 64, nh = (wave >> 1) * 32;
  int aoff[2][4], boff[2][2];
#pragma unroll
  for (int s = 0; s < 2; ++s) {
    int qc = s * 4 + q;
#pragma unroll
    for (int f = 0; f < 4; ++f) {
      int r = mh + f * 16 + m16;
      aoff[s][f] = r * 128 + ((qc ^ (r & 7)) * 16);
    }
#pragma unroll
    for (int j = 0; j < 2; ++j) {
      int r = nh + j * 16 + m16;
      boff[s][j] = r * 128 + ((qc ^ (r & 7)) * 16);
    }
  }

  f32x4 acc[2][4];
#pragma unroll
  for (int j = 0; j < 2; ++j)
#pragma unroll
    for (int f = 0; f < 4; ++f)
#pragma unroll
      for (int r = 0; r < 4; ++r) acc[j][f][r] = 0.f;

  for (int it = 0; it < IDIM / BK; ++it) {
    __syncthreads();
#pragma unroll
    for (int i = 0; i < 4; ++i) { gl2lds16(pA[i], lA[i]); pA[i] += BK * 2; }
#pragma unroll
    for (int i = 0; i < 2; ++i) { gl2lds16(pB[i], lB[i]); pB[i] += BK * 2; }
    __syncthreads();
#pragma unroll
    for (int s = 0; s < 2; ++s) {
      bf8 a[4], b2[2];
#pragma unroll
      for (int f = 0; f < 4; ++f)
        a[f] = *(const bf8*)((const char*)As + aoff[s][f]);
#pragma unroll
      for (int j = 0; j < 2; ++j)
        b2[j] = *(const bf8*)((const char*)Bs + boff[s][j]);
#pragma unroll
      for (int j = 0; j < 2; ++j)
#pragma unroll
        for (int f = 0; f < 4; ++f)
          acc[j][f] = __builtin_amdgcn_mfma_f32_16x16x32_bf16(a[f], b2[j], acc[j][f], 0, 0, 0);
    }
  }

  const int col0 = bn + nh + m16;
#pragma unroll
  for (int f = 0; f < 4; ++f)
#pragma unroll
    for (int r = 0; r < 4; ++r) {
      int row = mh + f * 16 + q * 4 + r;
      float* yrow = y + (size_t)(base + row) * HDIM + col0;
#pragma unroll
      for (int j = 0; j < 2; ++j)
        yrow[j * 16] = acc[j][f][r];      // plain store; pad rows never read
    }
}

// ---------------- combine: out[t] = y[p0] + y[p1] ----------------
__global__ __launch_bounds__(256) void combine_kernel(
    const float* __restrict__ y, const int* __restrict__ inv_map,
    float* __restrict__ out)
{
  const int t = blockIdx.x;
  const int tid = threadIdx.x;
  const int p0 = inv_map[2 * t], p1 = inv_map[2 * t + 1];
  const float* y0 = y + (size_t)p0 * HDIM + tid * 4;
  const float* y1 = y + (size_t)p1 * HDIM + tid * 4;
  float4 a = *(const float4*)y0;
  float4 b = *(const float4*)y1;
  float4 r; r.x = a.x + b.x; r.y = a.y + b.y; r.z = a.z + b.z; r.w = a.w + b.w;
  *(float4*)(out + (size_t)t * HDIM + tid * 4) = r;
}

extern "C" void kernel_launch(void* const* d_in, const int* in_sizes, int n_in,
                              void* d_out, int out_size, void* d_ws, size_t ws_size,
                              hipStream_t stream) {
  const float* x    = (const float*)d_in[0];
  const float* Wg   = (const float*)d_in[1];
  const float* Win  = (const float*)d_in[2];
  const float* Wv   = (const float*)d_in[3];
  const float* Wout = (const float*)d_in[4];
  float* out = (float*)d_out;
  float* logits_out = out + (size_t)T_TOK * HDIM;

  char* ws = (char*)d_ws;
  int*   sel      = (int*)(ws);
  float* wts      = (float*)(ws + (16 << 10));
  int*   slot_map = (int*)(ws + (32 << 10));
  float* slot_w   = (float*)(ws + (52 << 10));
  int*   meta     = (int*)(ws + (72 << 10));
  int*   inv_map  = (int*)(ws + (80 << 10));
  __bf16* xbf   = (__bf16*)(ws + (1ull << 20));     // 4 MB
  __bf16* WinT  = (__bf16*)(ws + (8ull << 20));     // 64 MB
  __bf16* WvT   = (__bf16*)(ws + (72ull << 20));    // 64 MB
  __bf16* WoutT = (__bf16*)(ws + (136ull << 20));   // 64 MB
  __bf16* actb  = (__bf16*)(ws + (200ull << 20));   // 40 MB
  // y aliases WinT: mlp1 (last reader of WinT) completes before mlp2 writes y
  float* y = (float*)(ws + (8ull << 20));           // 20 MB, slot-major

  router_kernel<<<T_TOK, 64, 0, stream>>>(x, Wg, logits_out, sel, wts, xbf);
  build_groups<<<1, 256, 0, stream>>>(sel, wts, slot_map, slot_w, meta, inv_map);
  prep_kernel<<<12288, 256, 0, stream>>>(Win, Wv, Wout, WinT, WvT, WoutT);
  moe_mlp1<<<MT_MAX * (IDIM / TN), 256, 0, stream>>>(xbf, WinT, WvT, slot_map, slot_w, meta, actb);
  moe_mlp2<<<MT_MAX * (HDIM / TN), 256, 0, stream>>>(actb, WoutT, meta, y);
  combine_kernel<<<T_TOK, 256, 0, stream>>>(y, inv_map, out);
}